// Round 2
// baseline (519.567 us; speedup 1.0000x reference)
//
#include <hip/hip_runtime.h>
#include <hip/hip_bf16.h>
#include <math.h>

// Problem constants
#define BD 8          // batch
#define SN 2048       // sequence length N
#define DM 1024       // d_model
#define NH 16         // heads
#define HD 64         // head dim
#define NS 11         // scales

typedef __attribute__((ext_vector_type(8))) short short8;
typedef __attribute__((ext_vector_type(4))) float floatx4;

// ---------------------------------------------------------------------------
// fp32 -> bf16 convert (vectorized by 4)
// ---------------------------------------------------------------------------
__global__ __launch_bounds__(256) void f2bf_kernel(const float* __restrict__ src,
                                                   __hip_bfloat16* __restrict__ dst,
                                                   int n4) {
    int i = blockIdx.x * 256 + threadIdx.x;
    if (i < n4) {
        const float4 v = reinterpret_cast<const float4*>(src)[i];
        union { __hip_bfloat16 h[4]; uint2 u; } cv;
        cv.h[0] = __float2bfloat16(v.x);
        cv.h[1] = __float2bfloat16(v.y);
        cv.h[2] = __float2bfloat16(v.z);
        cv.h[3] = __float2bfloat16(v.w);
        reinterpret_cast<uint2*>(dst)[i] = cv.u;
    }
}

// ---------------------------------------------------------------------------
// tiny softmaxes
// ---------------------------------------------------------------------------
__global__ void prep_kernel(const float* __restrict__ scale_gain,
                            const float* __restrict__ field_coupling,
                            float* __restrict__ gains,
                            float* __restrict__ cw) {
    int t = threadIdx.x;
    if (t < NH) {
        float m = -1e30f;
        for (int j = 0; j < NS; ++j) m = fmaxf(m, scale_gain[j * NH + t]);
        float e[NS]; float s = 0.f;
        for (int j = 0; j < NS; ++j) { e[j] = expf(scale_gain[j * NH + t] - m); s += e[j]; }
        float inv = 1.f / s;
        for (int j = 0; j < NS; ++j) gains[j * NH + t] = e[j] * inv;
    } else if (t < 2 * NH) {
        int r = t - NH;
        float m = -1e30f;
        for (int j = 0; j < NH; ++j) m = fmaxf(m, field_coupling[r * NH + j]);
        float e[NH]; float s = 0.f;
        for (int j = 0; j < NH; ++j) { e[j] = expf(field_coupling[r * NH + j] - m); s += e[j]; }
        float inv = 1.f / s;
        for (int j = 0; j < NH; ++j) cw[r * NH + j] = e[j] * inv;
    }
}

// ---------------------------------------------------------------------------
// bf16 MFMA GEMM: C[M,Nn] = A[M,K] @ Bw[Nn,K]^T + bias
// act=1 => sigmoid; bf16out=1 => store bf16 else fp32
// Block 256 threads = 4 waves, 64x64 tile, BK=64.
// mfma_f32_16x16x32_bf16 layouts (gfx950, HW-verified):
//   A frag: A[m = lane&15][k = (lane>>4)*8 + j]
//   B frag: Bw[n = lane&15][k = (lane>>4)*8 + j]
//   C/D  : col = lane&15, row = (lane>>4)*4 + reg
// ---------------------------------------------------------------------------
__global__ __launch_bounds__(256) void gemm_bf16_kernel(
    const __hip_bfloat16* __restrict__ A,
    const __hip_bfloat16* __restrict__ Bw,
    void* __restrict__ Cout,
    const float* __restrict__ bias,
    int M, int Nn, int K, int act, int bf16out) {
    __shared__ short As[64 * 72];   // rows padded to 72 (144B = 36 banks, 2-way max = free)
    __shared__ short Bs[64 * 72];

    const int tid = threadIdx.x;
    const int m0 = blockIdx.y * 64;
    const int n0 = blockIdx.x * 64;
    const int wave = tid >> 6;
    const int lane = tid & 63;
    const int wm = (wave >> 1) * 32;
    const int wn = (wave & 1) * 32;
    const int lrow = lane & 15;
    const int quad = lane >> 4;

    floatx4 acc[2][2];
    #pragma unroll
    for (int a = 0; a < 2; ++a)
        #pragma unroll
        for (int b = 0; b < 2; ++b) acc[a][b] = (floatx4){0.f, 0.f, 0.f, 0.f};

    for (int kt = 0; kt < K; kt += 64) {
        #pragma unroll
        for (int i = 0; i < 2; ++i) {
            int v = tid + i * 256;
            int row = v >> 3;
            int ch = (v & 7) * 8;
            *reinterpret_cast<short8*>(&As[row * 72 + ch]) =
                *reinterpret_cast<const short8*>(&A[(size_t)(m0 + row) * K + kt + ch]);
            *reinterpret_cast<short8*>(&Bs[row * 72 + ch]) =
                *reinterpret_cast<const short8*>(&Bw[(size_t)(n0 + row) * K + kt + ch]);
        }
        __syncthreads();
        #pragma unroll
        for (int kk = 0; kk < 64; kk += 32) {
            short8 a0 = *reinterpret_cast<const short8*>(&As[(wm + lrow) * 72 + kk + quad * 8]);
            short8 a1 = *reinterpret_cast<const short8*>(&As[(wm + 16 + lrow) * 72 + kk + quad * 8]);
            short8 b0 = *reinterpret_cast<const short8*>(&Bs[(wn + lrow) * 72 + kk + quad * 8]);
            short8 b1 = *reinterpret_cast<const short8*>(&Bs[(wn + 16 + lrow) * 72 + kk + quad * 8]);
            acc[0][0] = __builtin_amdgcn_mfma_f32_16x16x32_bf16(a0, b0, acc[0][0], 0, 0, 0);
            acc[0][1] = __builtin_amdgcn_mfma_f32_16x16x32_bf16(a0, b1, acc[0][1], 0, 0, 0);
            acc[1][0] = __builtin_amdgcn_mfma_f32_16x16x32_bf16(a1, b0, acc[1][0], 0, 0, 0);
            acc[1][1] = __builtin_amdgcn_mfma_f32_16x16x32_bf16(a1, b1, acc[1][1], 0, 0, 0);
        }
        __syncthreads();
    }

    #pragma unroll
    for (int mt = 0; mt < 2; ++mt) {
        #pragma unroll
        for (int nt = 0; nt < 2; ++nt) {
            int col = n0 + wn + nt * 16 + lrow;
            float bv = bias ? bias[col] : 0.f;
            #pragma unroll
            for (int i = 0; i < 4; ++i) {
                int row = m0 + wm + mt * 16 + quad * 4 + i;
                float val = acc[mt][nt][i] + bv;
                if (act == 1) val = 1.f / (1.f + expf(-val));
                if (bf16out)
                    ((__hip_bfloat16*)Cout)[(size_t)row * Nn + col] = __float2bfloat16(val);
                else
                    ((float*)Cout)[(size_t)row * Nn + col] = val;
            }
        }
    }
}

// ---------------------------------------------------------------------------
// fieldize: field[b, h*64+d, n] = v[b,n,h,d] * ||k[b,n,h,:]||   (bf16 in/out)
// kv row r=b*N+n: cols [0,1024)=k, [1024,2048)=v
// ---------------------------------------------------------------------------
__global__ __launch_bounds__(256) void fieldize_kernel(const __hip_bfloat16* __restrict__ kv,
                                                       __hip_bfloat16* __restrict__ field) {
    const int b = blockIdx.z, h = blockIdx.y, n0 = blockIdx.x * 64;
    __shared__ float kt[64][65];
    __shared__ float vt[64][65];
    __shared__ float mag[64];
    const int t = threadIdx.x;
    #pragma unroll
    for (int i = 0; i < 16; ++i) {
        int idx = t + i * 256;
        int nl = idx >> 6, d = idx & 63;
        size_t rbase = (size_t)(b * SN + n0 + nl) * 2048;
        kt[nl][d] = __bfloat162float(kv[rbase + h * 64 + d]);
        vt[nl][d] = __bfloat162float(kv[rbase + 1024 + h * 64 + d]);
    }
    __syncthreads();
    if (t < 64) {
        float s = 0.f;
        #pragma unroll
        for (int d = 0; d < 64; ++d) { float x = kt[t][d]; s += x * x; }
        mag[t] = sqrtf(s);
    }
    __syncthreads();
    #pragma unroll
    for (int i = 0; i < 16; ++i) {
        int idx = t + i * 256;
        int d = idx >> 6, nl = idx & 63;
        field[((size_t)b * DM + h * 64 + d) * SN + n0 + nl] =
            __float2bfloat16(vt[nl][d] * mag[nl]);
    }
}

// ---------------------------------------------------------------------------
// wavelet: per (b,c) row, out[n] = sum_j gains[j,h] * (D4 causal dilated taps)
// ---------------------------------------------------------------------------
__global__ __launch_bounds__(256) void wavelet_kernel(const __hip_bfloat16* __restrict__ field,
                                                      const float* __restrict__ gains,
                                                      __hip_bfloat16* __restrict__ wave) {
    const int bc = blockIdx.x;          // b*1024 + c
    const int c = bc & (DM - 1);
    const int h = c >> 6;
    __shared__ float row[SN];
    __shared__ float g[NS];
    const __hip_bfloat16* src = field + (size_t)bc * SN;
    const int t = threadIdx.x;
    for (int i = t; i < SN; i += 256) row[i] = __bfloat162float(src[i]);
    if (t < NS) g[t] = gains[t * NH + h];
    __syncthreads();
    const float d0 = 0.4829629131445341f, d1 = 0.8365163037378079f,
                d2 = 0.2241438680420134f, d3 = -0.1294095225512604f;
    __hip_bfloat16* dst = wave + (size_t)bc * SN;
    for (int n = t; n < SN; n += 256) {
        float acc = 0.f;
        float x3 = row[n];
        #pragma unroll
        for (int j = 0; j < NS; ++j) {
            int d = 1 << j;
            float x2 = (n >= d)     ? row[n - d]     : 0.f;
            float x1 = (n >= 2 * d) ? row[n - 2 * d] : 0.f;
            float x0 = (n >= 3 * d) ? row[n - 3 * d] : 0.f;
            acc += g[j] * (d0 * x0 + d1 * x1 + d2 * x2 + d3 * x3);
        }
        dst[n] = __float2bfloat16(acc);
    }
}

// ---------------------------------------------------------------------------
// head coupling: cpl[b, ho*64+d, n] = sum_hi cw[ho][hi] * wave[b, hi*64+d, n]
// ---------------------------------------------------------------------------
__global__ __launch_bounds__(256) void couple_kernel(const __hip_bfloat16* __restrict__ wave,
                                                     const float* __restrict__ cw,
                                                     __hip_bfloat16* __restrict__ cpl) {
    const int b = blockIdx.z, d = blockIdx.y;
    const int n = blockIdx.x * 256 + threadIdx.x;
    __shared__ float w[256];
    w[threadIdx.x] = cw[threadIdx.x];
    __syncthreads();
    size_t base = (size_t)b * DM * SN + (size_t)d * SN + n;
    float r[NH];
    #pragma unroll
    for (int hi = 0; hi < NH; ++hi) r[hi] = __bfloat162float(wave[base + (size_t)hi * 64 * SN]);
    #pragma unroll
    for (int ho = 0; ho < NH; ++ho) {
        float acc = 0.f;
        #pragma unroll
        for (int hi = 0; hi < NH; ++hi) acc += w[ho * 16 + hi] * r[hi];
        cpl[base + (size_t)ho * 64 * SN] = __float2bfloat16(acc);
    }
}

// ---------------------------------------------------------------------------
// transpose + gate: Ag[b*N+n, c] = bf16( cpl[b,c,n] * gate[b*N+n, c] )
// ---------------------------------------------------------------------------
__global__ __launch_bounds__(256) void transgate_kernel(const __hip_bfloat16* __restrict__ cpl,
                                                        const __hip_bfloat16* __restrict__ gate,
                                                        __hip_bfloat16* __restrict__ Ag) {
    const int b = blockIdx.z;
    const int c0 = blockIdx.y * 64, n0 = blockIdx.x * 64;
    __shared__ float tile[64][65];
    const int t = threadIdx.x;
    #pragma unroll
    for (int i = 0; i < 16; ++i) {
        int idx = t + i * 256;
        int ci = idx >> 6, nj = idx & 63;
        tile[ci][nj] = __bfloat162float(cpl[((size_t)b * DM + c0 + ci) * SN + n0 + nj]);
    }
    __syncthreads();
    #pragma unroll
    for (int i = 0; i < 16; ++i) {
        int idx = t + i * 256;
        int nj = idx >> 6, ci = idx & 63;
        size_t off = ((size_t)(b * SN + n0 + nj)) * DM + c0 + ci;
        Ag[off] = __float2bfloat16(tile[ci][nj] * __bfloat162float(gate[off]));
    }
}

// ---------------------------------------------------------------------------
// launch
// ws footprint: 142,608,384 B (fits 256 MiB ws); kv staged in d_out (67 MB)
// ---------------------------------------------------------------------------
extern "C" void kernel_launch(void* const* d_in, const int* in_sizes, int n_in,
                              void* d_out, int out_size, void* d_ws, size_t ws_size,
                              hipStream_t stream) {
    const float* x     = (const float*)d_in[0];
    const float* qkv_w = (const float*)d_in[1];
    const float* qkv_b = (const float*)d_in[2];
    const float* out_w = (const float*)d_in[3];
    const float* out_b = (const float*)d_in[4];
    const float* gate_w = (const float*)d_in[5];
    const float* gate_b = (const float*)d_in[6];
    const float* scale_gain = (const float*)d_in[7];
    const float* field_coupling = (const float*)d_in[8];

    char* ws = (char*)d_ws;
    const int M = BD * SN;          // 16384

    // ws layout (bytes) — total 142,608,384
    __hip_bfloat16* x_bf   = (__hip_bfloat16*)(ws);               // 33,554,432
    __hip_bfloat16* wkv_bf = (__hip_bfloat16*)(ws + 33554432);    //  4,194,304
    __hip_bfloat16* wg_bf  = (__hip_bfloat16*)(ws + 37748736);    //  2,097,152
    __hip_bfloat16* wo_bf  = (__hip_bfloat16*)(ws + 39845888);    //  2,097,152
    float* gains           = (float*)(ws + 41943040);             //        704
    float* cwbuf           = (float*)(ws + 41944064);             //      1,024
    __hip_bfloat16* gate_bf  = (__hip_bfloat16*)(ws + 41945088);  // 33,554,432
    __hip_bfloat16* field_bf = (__hip_bfloat16*)(ws + 75499520);  // 33,554,432
    __hip_bfloat16* wave_bf  = (__hip_bfloat16*)(ws + 109053952); // 33,554,432
    // aliases (lifetimes verified):
    __hip_bfloat16* kv_bf  = (__hip_bfloat16*)d_out;  // [16384,2048] bf16 = 67MB = d_out size; dead before final GEMM writes d_out
    __hip_bfloat16* cpl_bf = field_bf;                // field dead after wavelet
    __hip_bfloat16* Ag     = x_bf;                    // x dead after the two x-GEMMs
    float* out = (float*)d_out;

    // converts
    f2bf_kernel<<<(M * DM / 4 + 255) / 256, 256, 0, stream>>>(x, x_bf, M * DM / 4);
    f2bf_kernel<<<(2 * DM * DM / 4 + 255) / 256, 256, 0, stream>>>(qkv_w + (size_t)DM * DM, wkv_bf, 2 * DM * DM / 4);
    f2bf_kernel<<<(DM * DM / 4 + 255) / 256, 256, 0, stream>>>(gate_w, wg_bf, DM * DM / 4);
    f2bf_kernel<<<(DM * DM / 4 + 255) / 256, 256, 0, stream>>>(out_w, wo_bf, DM * DM / 4);

    prep_kernel<<<1, 64, 0, stream>>>(scale_gain, field_coupling, gains, cwbuf);

    // kv = bf16(x @ W_kv^T + b_kv)  [16384, 2048] -> d_out scratch
    {
        dim3 grid(2 * DM / 64, M / 64);
        gemm_bf16_kernel<<<grid, 256, 0, stream>>>(x_bf, wkv_bf, kv_bf, qkv_b + DM, M, 2 * DM, DM, 0, 1);
    }
    // gate = bf16(sigmoid(x @ gate_w^T + gate_b))  [16384, 1024]
    {
        dim3 grid(DM / 64, M / 64);
        gemm_bf16_kernel<<<grid, 256, 0, stream>>>(x_bf, wg_bf, gate_bf, gate_b, M, DM, DM, 1, 1);
    }
    // field[b,c,n]
    {
        dim3 grid(SN / 64, NH, BD);
        fieldize_kernel<<<grid, 256, 0, stream>>>(kv_bf, field_bf);
    }
    // wavelet
    wavelet_kernel<<<BD * DM, 256, 0, stream>>>(field_bf, gains, wave_bf);
    // coupling
    {
        dim3 grid(SN / 256, HD, BD);
        couple_kernel<<<grid, 256, 0, stream>>>(wave_bf, cwbuf, cpl_bf);
    }
    // transpose + gate -> Ag bf16 [16384, 1024]
    {
        dim3 grid(SN / 64, DM / 64, BD);
        transgate_kernel<<<grid, 256, 0, stream>>>(cpl_bf, gate_bf, Ag);
    }
    // out = Ag @ out_w^T + out_b   (fp32 -> d_out)
    {
        dim3 grid(DM / 64, M / 64);
        gemm_bf16_kernel<<<grid, 256, 0, stream>>>(Ag, wo_bf, out, out_b, M, DM, DM, 0, 0);
    }
}